// Round 8
// baseline (233.005 us; speedup 1.0000x reference)
//
#include <hip/hip_runtime.h>
#include <math.h>

// Causal depthwise conv1d K=4 + SiLU. x (B=4, T=4096, C=2048) fp32, kernel (4, C) fp32.
// y[b,t,c] = silu( sum_j k[j,c] * x[b,t-j,c] ), zero-padded; next_cache = x[:, T-3:, :].
//
// R9 post-mortem: TLP saturated (TG=2/16384blk = 77us > TG=4/8192blk = 72us). Every
//   VGPR-based load schedule gets serialized by the compiler (VGPR 32/36/56/36 across
//   4 attempts); thread count was the only lever and it's topped out at ~3 TB/s vs
//   the ~35us compulsory floor.
// R10: global_load_lds DMA staging -- loads with NO destination register cannot be
//   serialized by the register allocator. Each wave issues 11 x 1KB DMA loads
//   back-to-back into LDS (structurally in flight until the single __syncthreads
//   drain), then computes from LDS. Block = 256 thr x 256 c4 x TT=8 rows; 11 staged
//   rows = 44KB LDS -> 3 blocks/CU; inter-block overlap hides the barrier (m114).
//   Attribution check: LDS_Block_Size 0 -> 45056.

#define B_     4
#define T_     4096
#define C_     2048
#define K_     4
#define C4_    (C_ / 4)       // 512 float4 groups per row
#define TT_    8              // output rows per block
#define NTG_   (T_ / TT_)     // 512 t-groups
#define HC4_   256            // c4 per block (half the channels)
#define ROWS_  (TT_ + K_ - 1) // 11 staged rows

typedef float f4 __attribute__((ext_vector_type(4)));

__device__ __forceinline__ float silu_f(float v) {
    return v * __builtin_amdgcn_rcpf(1.f + __expf(-v));
}

__global__ __launch_bounds__(256, 3) void dwconv_silu_kernel(
    const f4* __restrict__ x,      // [B, T, C4]
    const f4* __restrict__ kern,   // [K, C4]
    f4* __restrict__ y,            // [B, T, C4]
    f4* __restrict__ cache)        // [B, K-1, C4]
{
    __shared__ f4 tile[ROWS_ * HC4_];   // 11 * 256 * 16B = 44 KB

    const int bid  = blockIdx.x;
    const int half = bid & 1;                 // which 256-wide c4 half
    const int tgrp = (bid >> 1) & (NTG_ - 1); // t-group
    const int b    = bid >> 10;               // 1 bit half + 9 bits tgrp
    const int t0   = tgrp * TT_;
    const int tid  = threadIdx.x;
    const int wv   = tid >> 6;                // wave id 0..3
    const int c4   = half * HC4_ + tid;

    // kern in VGPRs (L1/L2-hot, oldest in vmcnt queue, drained at the barrier).
    const f4 k0 = kern[0 * C4_ + c4];
    const f4 k1 = kern[1 * C4_ + c4];
    const f4 k2 = kern[2 * C4_ + c4];
    const f4 k3 = kern[3 * C4_ + c4];

    // Stage rows t0-3 .. t0+TT-1 into LDS via DMA. LDS dest is wave-uniform base
    // + lane*16 (HW rule); per-lane global src supplies lane l's c4 = base+wv*64+l.
    const f4* xb = x + ((size_t)b * T_ + t0 - (K_ - 1)) * C4_ + c4; // row r at xb[r*C4_]
    int rstart = 0;
    if (t0 == 0) {                       // 8 of 4096 blocks; block-uniform
        const f4 z = {0.f, 0.f, 0.f, 0.f};
        tile[0 * HC4_ + tid] = z;
        tile[1 * HC4_ + tid] = z;
        tile[2 * HC4_ + tid] = z;
        rstart = K_ - 1;
    }
    #pragma unroll
    for (int r = 0; r < ROWS_; ++r) {
        if (r >= rstart) {
            __builtin_amdgcn_global_load_lds(
                (const __attribute__((address_space(1))) void*)(xb + (size_t)r * C4_),
                (__attribute__((address_space(3))) void*)&tile[r * HC4_ + wv * 64],
                16 /*bytes, literal*/, 0 /*offset*/, 0 /*aux*/);
        }
    }
    __syncthreads();   // single drain: all 11 DMA loads were concurrently in flight

    // Compute from LDS: contiguous ds_read_b128 (lane l reads +l*16 -> no conflicts).
    f4 w3 = tile[0 * HC4_ + tid];
    f4 w2 = tile[1 * HC4_ + tid];
    f4 w1 = tile[2 * HC4_ + tid];

    f4* yp = y + ((size_t)b * T_ + t0) * C4_ + c4;
    #pragma unroll
    for (int i = 0; i < TT_; ++i) {
        const f4 a = tile[(K_ - 1 + i) * HC4_ + tid];
        f4 r;
        r.x = fmaf(k0.x, a.x, fmaf(k1.x, w1.x, fmaf(k2.x, w2.x, k3.x * w3.x)));
        r.y = fmaf(k0.y, a.y, fmaf(k1.y, w1.y, fmaf(k2.y, w2.y, k3.y * w3.y)));
        r.z = fmaf(k0.z, a.z, fmaf(k1.z, w1.z, fmaf(k2.z, w2.z, k3.z * w3.z)));
        r.w = fmaf(k0.w, a.w, fmaf(k1.w, w1.w, fmaf(k2.w, w2.w, k3.w * w3.w)));
        r.x = silu_f(r.x); r.y = silu_f(r.y); r.z = silu_f(r.z); r.w = silu_f(r.w);
        yp[i * C4_] = r;
        w3 = w2; w2 = w1; w1 = a;
    }

    // Fused next_cache = x[:, T-3:, :] from the staged tile of the last t-group:
    // x[T-3+j] = tile[TT_+j] (row index r maps to t = t0-3+r).
    if (tgrp == NTG_ - 1) {
        f4* cb = cache + (size_t)b * (K_ - 1) * C4_ + c4;
        cb[0 * C4_] = tile[(TT_ + 0) * HC4_ + tid];
        cb[1 * C4_] = tile[(TT_ + 1) * HC4_ + tid];
        cb[2 * C4_] = tile[(TT_ + 2) * HC4_ + tid];
    }
}

extern "C" void kernel_launch(void* const* d_in, const int* in_sizes, int n_in,
                              void* d_out, int out_size, void* d_ws, size_t ws_size,
                              hipStream_t stream)
{
    const f4* x    = (const f4*)d_in[0];
    const f4* kern = (const f4*)d_in[1];
    float*    out  = (float*)d_out;

    f4* y     = (f4*)out;
    f4* cache = (f4*)(out + (size_t)B_ * T_ * C_);

    dim3 grid(B_ * NTG_ * 2);   // 4096 blocks
    dim3 block(256);
    dwconv_silu_kernel<<<grid, block, 0, stream>>>(x, kern, y, cache);
}